// Round 12
// baseline (186.550 us; speedup 1.0000x reference)
//
#include <hip/hip_runtime.h>

// Problem constants (from reference setup_inputs):
//   image:  (B=4, H=512, W=640, C=16) fp32   (83.9 MB)
//   depth:  (B, H, W) fp32                    (5.2 MB)
//   proj:   (B, 4, 4) fp32
//   out:    (B, H, W, C) fp32                 (83.9 MB)
constexpr int B  = 4;
constexpr int H  = 512;
constexpr int Wd = 640;
constexpr int NPIX_IMG = H * Wd;
constexpr int BLOCK  = 256;
constexpr int STRIP  = 128;                 // output pixels per block in x
constexpr int NSTEP  = 16;                  // output rows per block
constexpr int STRIPS = Wd / STRIP;          // 5
constexpr int LAYERS = H / NSTEP;           // 32
constexpr int GRID   = B * LAYERS * STRIPS; // 640 blocks -> ALL resident (3/CU by LDS)
constexpr int XM     = 32;                  // left margin of staged window
constexpr int SW     = 192;                 // staged window width (pixels)
constexpr int SEGF4  = SW * 4;              // 768 float4 slots per staged row
constexpr int RING   = 4;                   // rows in LDS ring (slot = row & 3)
static_assert(STRIPS * STRIP == Wd && LAYERS * NSTEP == H, "exact tiling");

typedef float f32x4 __attribute__((ext_vector_type(4)));

// Round-12 theory: every structure that leaves a COLD data-dependent load on
// the per-pixel chain (depth->coords->gather) pins at 49-54us. Here nothing
// is ever waited on cold: the staging schedule is computed from the MATRIX
// ALONE (no depth dependence), rows are reg-loaded one step ahead and
// ds_written at step end (compiler emits precise vmcnt, never vmcnt(0)),
// depth for step s+1 loads during step s, and gathers become LDS reads.
// A value-checked fallback (exec-masked global gather) keeps the kernel
// correct for ANY projection matrix; with the given near-identity matrices
// the 4-row x 192-px window covers ~100% of corners.
__global__ __launch_bounds__(256) void depth_project_kernel(
    const float* __restrict__ image,
    const float* __restrict__ depth,
    const float* __restrict__ proj,
    float4* __restrict__ out)
{
    __shared__ f32x4 tile[RING * SEGF4];    // 49,152 B

    const int blk   = blockIdx.x;
    const int b     = blk / (LAYERS * STRIPS);
    const int r2    = blk % (LAYERS * STRIPS);
    const int layer = r2 / STRIPS;
    const int strip = r2 % STRIPS;
    const int h0    = layer * NSTEP;
    const int wb    = strip * STRIP;
    const int xlo   = wb - XM;

    const int tix = threadIdx.x;
    const int c4  = tix & 3;                // float4 group of the 16 channels
    const int pl  = tix >> 2;               // pixel within 64-px sub-iter

    const float* P = proj + b * 16;         // uniform -> scalar loads
    const float p0=P[0],p1=P[1],p2=P[2],p3=P[3],p4=P[4],p5=P[5],
                p6=P[6],p7=P[7],p8=P[8],p9=P[9],p10=P[10],p11=P[11];

    const f32x4* imgv = (const f32x4*)image;
    const int ibase = b * (NPIX_IMG * 4);   // float4 units
    f32x4* out_v = (f32x4*)out;

    // matrix-only row predictor: floor(cy at strip center, d=1) - 1 (uniform)
    auto predict = [&](int hh) -> int {
        const float xc = (float)(wb + 64), yc = (float)hh;
        float sy = (p4 * xc + p5 * yc + p6) + p7;
        float sz = (p8 * xc + p9 * yc + p10) + p11;
        float cy = sy / sz;
        cy = fminf(fmaxf(cy, -1.0e6f), 1.0e6f);
        return (int)floorf(cy) - 1;
    };

    // reg-load one image row segment (3 x f32x4 per thread, 768 slots total)
    auto load_row = [&](int r, f32x4& a, f32x4& c, f32x4& e) {
        const int rc = min(max(r, 0), H - 1);
        const int rb = ibase + rc * (Wd * 4);
        {   int idx = tix;       int col = idx >> 2, cc = idx & 3;
            int xc = min(max(xlo + col, 0), Wd - 1);
            a = imgv[rb + xc * 4 + cc]; }
        {   int idx = tix + 256; int col = idx >> 2, cc = idx & 3;
            int xc = min(max(xlo + col, 0), Wd - 1);
            c = imgv[rb + xc * 4 + cc]; }
        {   int idx = tix + 512; int col = idx >> 2, cc = idx & 3;
            int xc = min(max(xlo + col, 0), Wd - 1);
            e = imgv[rb + xc * 4 + cc]; }
    };
    auto write_row = [&](int r, const f32x4& a, const f32x4& c, const f32x4& e) {
        const int slot = r & 3;
        tile[slot * SEGF4 + tix]       = a;
        tile[slot * SEGF4 + tix + 256] = c;
        tile[slot * SEGF4 + tix + 512] = e;
    };

    // ---- prologue: stage rows lo..lo+3 (one-time synchronous staging) ----
    int lo_cur = min(max(predict(h0), -4), H);
    f32x4 rA0,rA1,rA2, rB0,rB1,rB2, rC0,rC1,rC2, rD0,rD1,rD2;
    load_row(lo_cur + 0, rA0, rA1, rA2);
    load_row(lo_cur + 1, rB0, rB1, rB2);
    load_row(lo_cur + 2, rC0, rC1, rC2);
    load_row(lo_cur + 3, rD0, rD1, rD2);
    // first step's depth (both 64-px sub-iters)
    float d0 = depth[(b * H + h0) * Wd + wb + pl];
    float d1 = depth[(b * H + h0) * Wd + wb + 64 + pl];
    write_row(lo_cur + 0, rA0, rA1, rA2);
    write_row(lo_cur + 1, rB0, rB1, rB2);
    write_row(lo_cur + 2, rC0, rC1, rC2);
    write_row(lo_cur + 3, rD0, rD1, rD2);
    __syncthreads();

    f32x4 pA0,pA1,pA2, pB0,pB1,pB2;         // pending staged rows (<=2)

    for (int s = 0; s < NSTEP; ++s) {
        // next-step schedule (uniform, matrix-only; monotone-clamped)
        const int lo_next = min(max(predict(h0 + s + 1), lo_cur), lo_cur + 2);
        const int npend = lo_next - lo_cur;             // 0..2 new rows

        // issue next-step loads EARLY (consumed at the ds_write after the
        // barrier -> compiler's vmcnt covers them with the whole compute phase)
        if (npend >= 1) load_row(lo_cur + 4, pA0, pA1, pA2);
        if (npend >= 2) load_row(lo_cur + 5, pB0, pB1, pB2);
        const int hn = h0 + min(s + 1, NSTEP - 1);
        const float dn0 = depth[(b * H + hn) * Wd + wb + pl];
        const float dn1 = depth[(b * H + hn) * Wd + wb + 64 + pl];

        // ---- compute this row: two 64-px sub-iters ----
        const float y = (float)(h0 + s);
#pragma unroll
        for (int k = 0; k < 2; ++k) {
            const int   px = wb + (k << 6) + pl;
            const float dd = k ? d1 : d0;
            const float x  = (float)px;

            float sx = (p0 * x + p1 * y + p2)  * dd + p3;
            float sy = (p4 * x + p5 * y + p6)  * dd + p7;
            float sz = (p8 * x + p9 * y + p10) * dd + p11;
            float cx = sx / sz, cy = sy / sz;

            float x0f = floorf(cx), y0f = floorf(cy);
            float wx1 = cx - x0f,   wy1 = cy - y0f;
            float wx0 = 1.0f - wx1, wy0 = 1.0f - wy1;
            int x0 = (int)x0f, y0 = (int)y0f;
            int x1 = x0 + 1,   y1 = y0 + 1;

            float vx0 = (x0 >= 0 && x0 < Wd) ? 1.0f : 0.0f;
            float vx1 = (x1 >= 0 && x1 < Wd) ? 1.0f : 0.0f;
            float vy0 = (y0 >= 0 && y0 < H)  ? 1.0f : 0.0f;
            float vy1 = (y1 >= 0 && y1 < H)  ? 1.0f : 0.0f;

            int x0c = min(max(x0, 0), Wd - 1), x1c = min(max(x1, 0), Wd - 1);
            int y0c = min(max(y0, 0), H - 1),  y1c = min(max(y1, 0), H - 1);

            float w00 = wy0 * wx0 * vy0 * vx0, w01 = wy0 * wx1 * vy0 * vx1;
            float w10 = wy1 * wx0 * vy1 * vx0, w11 = wy1 * wx1 * vy1 * vx1;

            // LDS window hit test (exact, value-checked)
            const int j0 = x0c - xlo, j1 = x1c - xlo;
            const bool jok0 = (unsigned)j0 < (unsigned)SW;
            const bool jok1 = (unsigned)j1 < (unsigned)SW;
            const bool rok0 = (unsigned)(y0c - lo_cur) < (unsigned)RING;
            const bool rok1 = (unsigned)(y1c - lo_cur) < (unsigned)RING;
            const int s0 = y0c & 3, s1 = y1c & 3;
            const int j0s = jok0 ? j0 : 0, j1s = jok1 ? j1 : 0;

            f32x4 g00 = tile[s0 * SEGF4 + j0s * 4 + c4];
            f32x4 g01 = tile[s0 * SEGF4 + j1s * 4 + c4];
            f32x4 g10 = tile[s1 * SEGF4 + j0s * 4 + c4];
            f32x4 g11 = tile[s1 * SEGF4 + j1s * 4 + c4];

            const bool c00 = rok0 && jok0, c01 = rok0 && jok1;
            const bool c10 = rok1 && jok0, c11 = rok1 && jok1;
            if (!(c00 && c01 && c10 && c11)) {   // rare: predictor miss/border
                const f32x4* ib = imgv + ibase;
                if (!c00) g00 = ib[(y0c * Wd + x0c) * 4 + c4];
                if (!c01) g01 = ib[(y0c * Wd + x1c) * 4 + c4];
                if (!c10) g10 = ib[(y1c * Wd + x0c) * 4 + c4];
                if (!c11) g11 = ib[(y1c * Wd + x1c) * 4 + c4];
            }

            f32x4 r = g00 * w00 + g01 * w01 + g10 * w10 + g11 * w11;
            __builtin_nontemporal_store(r, out_v + ((b * H + h0 + s) * Wd + px) * 4 + c4);
        }

        __syncthreads();                          // protect ring before overwrite
        if (npend >= 1) write_row(lo_cur + 4, pA0, pA1, pA2);
        if (npend >= 2) write_row(lo_cur + 5, pB0, pB1, pB2);
        __syncthreads();                          // writes visible for next step

        lo_cur = lo_next;
        d0 = dn0; d1 = dn1;
    }
}

extern "C" void kernel_launch(void* const* d_in, const int* in_sizes, int n_in,
                              void* d_out, int out_size, void* d_ws, size_t ws_size,
                              hipStream_t stream) {
    const float* image = (const float*)d_in[0];
    const float* depth = (const float*)d_in[1];
    const float* proj  = (const float*)d_in[2];
    float4* out = (float4*)d_out;

    depth_project_kernel<<<GRID, BLOCK, 0, stream>>>(image, depth, proj, out);
}

// Round 13
// 154.924 us; speedup vs baseline: 1.2041x; 1.2041x over previous
//
#include <hip/hip_runtime.h>

// Problem constants (from reference setup_inputs):
//   image:  (B=4, H=512, W=640, C=16) fp32   (83.9 MB)
//   depth:  (B, H, W) fp32                    (5.2 MB)
//   proj:   (B, 4, 4) fp32
//   out:    (B, H, W, C) fp32                 (83.9 MB)
constexpr int B  = 4;
constexpr int H  = 512;
constexpr int Wd = 640;
constexpr int NPIX_IMG = H * Wd;
constexpr int BLOCK = 256;
constexpr int PIXB  = BLOCK / 4;            // 64 pixels per block
constexpr int BPR   = Wd / PIXB;            // 10 blocks per row (exact)
constexpr int BLOCKS_PER_IMG = H * BPR;     // 5120
constexpr int GRID  = B * BLOCKS_PER_IMG;   // 20480 blocks
constexpr int KPF   = 2048;                 // prefetch lead = ~1 residency
                                            // generation; %8==0 keeps XCD
static_assert(Wd % PIXB == 0, "block tiles a row exactly");
static_assert(KPF % 8 == 0, "XCD-preserving prefetch lead");

// Native vector type for nontemporal builtins (HIP_vector_type is rejected).
typedef float f32x4 __attribute__((ext_vector_type(4)));

// Round-13 theory: r8's prefetch was issued BEFORE the gathers; since vmcnt
// is an in-order counter, the gather wait drained the ~900cy HBM prefetch
// every time — the wave stalled on its own prefetch (why r8 gained only
// ~3%). Fix: issue the prefetch AFTER the gathers (sched_barrier(0) pins
// the compiler from hoisting it), so the gather wait covers only
// {depth: done, gathers: L2-warm ~300cy}, and the prefetch stays in
// flight until after the store. KPF=2048 (one full residency generation)
// guarantees the warming block COMPLETED before the consumer starts.
__global__ __launch_bounds__(256) void depth_project_kernel(
    const float* __restrict__ image,
    const float* __restrict__ depth,
    const float* __restrict__ proj,
    float4* __restrict__ out)
{
    const int blk = blockIdx.x;
    const int tix = threadIdx.x;

    // b, h block-uniform: SALU math, proj reads become s_loads.
    const int b   = blk / BLOCKS_PER_IMG;
    const int rem = blk % BLOCKS_PER_IMG;
    const int h   = rem / BPR;
    const int wb  = (rem % BPR) * PIXB;

    const int c4 = tix & 3;
    const int pl = tix >> 2;
    const int w  = wb + pl;
    const int pix = (b * H + h) * Wd + w;

    // critical-path depth load — oldest in the vmcnt queue, L2-warm
    // (warmed by block blk-KPF's depth prefetch)
    const float d = depth[pix];

    const float* P = proj + b * 16;   // uniform -> scalar loads
    const float x = (float)w;
    const float y = (float)h;

    float sx = (P[0] * x + P[1] * y + P[2])  * d + P[3];
    float sy = (P[4] * x + P[5] * y + P[6])  * d + P[7];
    float sz = (P[8] * x + P[9] * y + P[10]) * d + P[11];
    float cx = sx / sz;
    float cy = sy / sz;

    float x0f = floorf(cx), y0f = floorf(cy);
    float wx1 = cx - x0f,   wy1 = cy - y0f;
    float wx0 = 1.0f - wx1, wy0 = 1.0f - wy1;
    int x0 = (int)x0f, y0 = (int)y0f;
    int x1 = x0 + 1,   y1 = y0 + 1;

    float vx0 = (x0 >= 0 && x0 < Wd) ? 1.0f : 0.0f;
    float vx1 = (x1 >= 0 && x1 < Wd) ? 1.0f : 0.0f;
    float vy0 = (y0 >= 0 && y0 < H)  ? 1.0f : 0.0f;
    float vy1 = (y1 >= 0 && y1 < H)  ? 1.0f : 0.0f;

    int x0c = min(max(x0, 0), Wd - 1);
    int x1c = min(max(x1, 0), Wd - 1);
    int y0c = min(max(y0, 0), H - 1);
    int y1c = min(max(y1, 0), H - 1);

    float w00 = wy0 * wx0 * vy0 * vx0;
    float w01 = wy0 * wx1 * vy0 * vx1;
    float w10 = wy1 * wx0 * vy1 * vx0;
    float w11 = wy1 * wx1 * vy1 * vx1;

    // gathers: L2/L3-warm thanks to block (blk-KPF)'s sequential prefetch
    const float4* img4 = (const float4*)image;
    const int base_b = b * (NPIX_IMG * 4);   // float4 units
    float4 g00 = img4[base_b + (y0c * Wd + x0c) * 4 + c4];
    float4 g01 = img4[base_b + (y0c * Wd + x1c) * 4 + c4];
    float4 g10 = img4[base_b + (y1c * Wd + x0c) * 4 + c4];
    float4 g11 = img4[base_b + (y1c * Wd + x1c) * 4 + c4];

    // ---- ORDER PIN: nothing below may be scheduled above this point.
    // The prefetch therefore issues YOUNGER than the gathers, so the
    // gather wait (in-order vmcnt) never drains the prefetch.
    __builtin_amdgcn_sched_barrier(0);

    // fire-and-forget prefetch of block (blk+KPF)'s working set:
    // image chunk (256 x 16B = its 64 pixels) + its 64 depth values.
    const f32x4* img_v = (const f32x4*)image;
    f32x4 pf = {0.0f, 0.0f, 0.0f, 0.0f};
    float pfd = 0.0f;
    const int pblk = blk + KPF;
    if (pblk < GRID) {
        pf = img_v[pblk * BLOCK + tix];
        if (tix < PIXB) pfd = depth[pblk * PIXB + tix];
    }

    f32x4 r;
    r.x = g00.x * w00 + g01.x * w01 + g10.x * w10 + g11.x * w11;
    r.y = g00.y * w00 + g01.y * w01 + g10.y * w10 + g11.y * w11;
    r.z = g00.z * w00 + g01.z * w01 + g10.z * w10 + g11.z * w11;
    r.w = g00.w * w00 + g01.w * w01 + g10.w * w10 + g11.w * w11;

    // write-once stream: nontemporal so stores don't evict the warm image
    f32x4* out_v = (f32x4*)out;
    __builtin_nontemporal_store(r, out_v + pix * 4 + c4);

    // consume the prefetch LAST — the only point that waits on it is after
    // the store, when the wave has no work left.
    asm volatile("" :: "v"(pf.x), "v"(pf.y), "v"(pf.z), "v"(pf.w), "v"(pfd));
}

extern "C" void kernel_launch(void* const* d_in, const int* in_sizes, int n_in,
                              void* d_out, int out_size, void* d_ws, size_t ws_size,
                              hipStream_t stream) {
    const float* image = (const float*)d_in[0];
    const float* depth = (const float*)d_in[1];
    const float* proj  = (const float*)d_in[2];
    float4* out = (float4*)d_out;

    depth_project_kernel<<<GRID, BLOCK, 0, stream>>>(image, depth, proj, out);
}